// Round 2
// baseline (310.327 us; speedup 1.0000x reference)
//
#include <hip/hip_runtime.h>
#include <hip/hip_bf16.h>

#define CDIM 32
#define KCODES 4096
#define NROWS 65536
#define HW 4096
#define KP 8
#define KSLICE (KCODES / KP)      // 512 codes per partition
#define TPB 256
#define RPT 2                      // rows per thread
#define ROWS_PER_BLOCK (TPB * RPT) // 512
#define TILE 64                    // codes staged per LDS tile
#define BETA 0.25f

// ---- workspace layout (bytes) ----
#define LOSS_OFF  0u
#define BIAS_OFF  256u
#define SCORE_OFF (256u + KCODES * 4u)                       // 16640
#define IDX_OFF   (SCORE_OFF + (unsigned)KP * NROWS * 4u)    // 2113792
#define Z2_OFF    (IDX_OFF + (unsigned)KP * NROWS * 4u)      // 4210944

// bias[k] = -0.5 * ||e_k||^2
__global__ __launch_bounds__(256) void vq_bias(const float* __restrict__ table,
                                               float* __restrict__ bias) {
    int k = blockIdx.x * 256 + threadIdx.x;
    if (k >= KCODES) return;
    const float4* row = (const float4*)(table + (size_t)k * CDIM);
    float s = 0.f;
#pragma unroll
    for (int i = 0; i < CDIM / 4; ++i) {
        float4 v = row[i];
        s = fmaf(v.x, v.x, s);
        s = fmaf(v.y, v.y, s);
        s = fmaf(v.z, v.z, s);
        s = fmaf(v.w, v.w, s);
    }
    bias[k] = -0.5f * s;
}

__global__ __launch_bounds__(TPB) void vq_main(const float* __restrict__ z,
                                               const float* __restrict__ table,
                                               const float* __restrict__ bias,
                                               float* __restrict__ scores,
                                               int* __restrict__ idxs,
                                               float* __restrict__ z2out) {
    __shared__ float elds[TILE * CDIM]; // 8 KB
    __shared__ float blds[TILE];

    const int t = threadIdx.x;
    const int rb = blockIdx.x * ROWS_PER_BLOCK;
    const int kp = blockIdx.y;
    const int k0 = kp * KSLICE;
    const int n0 = rb + t;
    const int n1 = n0 + TPB;
    const int b  = rb >> 12;          // batch index, uniform across block
    const int hw0 = n0 & (HW - 1);
    const int hw1 = n1 & (HW - 1);
    const float* zb = z + (size_t)b * CDIM * HW;

    // load both z rows into registers (coalesced per-c plane)
    float z0[CDIM], z1[CDIM];
#pragma unroll
    for (int c = 0; c < CDIM; ++c) {
        z0[c] = zb[c * HW + hw0];
        z1[c] = zb[c * HW + hw1];
    }

    float best0 = -1e30f, best1 = -1e30f;
    int bi0 = 0, bi1 = 0;

    for (int kt = 0; kt < KSLICE; kt += TILE) {
        __syncthreads();
        // stage TILE codes: TILE*CDIM floats = 512 float4s, 256 threads x 2
        const float4* src = (const float4*)(table + (size_t)(k0 + kt) * CDIM);
        float4* dst = (float4*)elds;
        dst[t] = src[t];
        dst[t + TPB] = src[t + TPB];
        if (t < TILE) blds[t] = bias[k0 + kt + t];
        __syncthreads();

#pragma unroll 2
        for (int kk = 0; kk < TILE; ++kk) {
            float a0 = blds[kk];
            float a1 = a0;
            const float* e = elds + kk * CDIM;
#pragma unroll
            for (int c = 0; c < CDIM; ++c) {
                float ev = e[c];
                a0 = fmaf(z0[c], ev, a0);
                a1 = fmaf(z1[c], ev, a1);
            }
            int k = k0 + kt + kk;
            if (a0 > best0) { best0 = a0; bi0 = k; } // strict >: keep first (lowest k)
            if (a1 > best1) { best1 = a1; bi1 = k; }
        }
    }

    scores[kp * NROWS + n0] = best0;
    scores[kp * NROWS + n1] = best1;
    idxs[kp * NROWS + n0] = bi0;
    idxs[kp * NROWS + n1] = bi1;

    if (kp == 0) {
        float s0 = 0.f, s1 = 0.f;
#pragma unroll
        for (int c = 0; c < CDIM; ++c) {
            s0 = fmaf(z0[c], z0[c], s0);
            s1 = fmaf(z1[c], z1[c], s1);
        }
        z2out[n0] = s0;
        z2out[n1] = s1;
    }
}

__global__ __launch_bounds__(256) void vq_combine(const float* __restrict__ scores,
                                                  const int* __restrict__ idxs,
                                                  const float* __restrict__ z2,
                                                  const float* __restrict__ table,
                                                  float* __restrict__ out_zq,
                                                  float* __restrict__ out_idx,
                                                  float* __restrict__ loss) {
    const int n = blockIdx.x * 256 + threadIdx.x;
    float best = -1e30f;
    int bi = 0;
#pragma unroll
    for (int kp = 0; kp < KP; ++kp) {   // ascending partition => lowest k wins ties
        float s = scores[kp * NROWS + n];
        int i = idxs[kp * NROWS + n];
        if (s > best) { best = s; bi = i; }
    }

    out_idx[n] = (float)bi;

    const int b = n >> 12;
    const int hw = n & (HW - 1);
    const float4* trow = (const float4*)(table + (size_t)bi * CDIM);
#pragma unroll
    for (int c4 = 0; c4 < CDIM / 4; ++c4) {
        float4 v = trow[c4];
        float* o = out_zq + ((size_t)(b * CDIM + c4 * 4) * HW + hw);
        o[0]        = v.x;
        o[HW]       = v.y;
        o[2 * HW]   = v.z;
        o[3 * HW]   = v.w;
    }

    // distance of chosen code: ||z||^2 - 2*score  (>=0 up to rounding)
    float d = fmaxf(z2[n] - 2.0f * best, 0.0f);
#pragma unroll
    for (int off = 32; off; off >>= 1) d += __shfl_down(d, off);
    if ((threadIdx.x & 63) == 0) atomicAdd(loss, d);
}

__global__ void vq_finalize(const float* __restrict__ loss,
                            float* __restrict__ out_loss) {
    out_loss[0] = loss[0] * (1.0f + BETA) / (float)((size_t)NROWS * CDIM);
}

extern "C" void kernel_launch(void* const* d_in, const int* in_sizes, int n_in,
                              void* d_out, int out_size, void* d_ws, size_t ws_size,
                              hipStream_t stream) {
    const float* z     = (const float*)d_in[0];
    const float* table = (const float*)d_in[1];

    char* ws = (char*)d_ws;
    float* loss   = (float*)(ws + LOSS_OFF);
    float* bias   = (float*)(ws + BIAS_OFF);
    float* scores = (float*)(ws + SCORE_OFF);
    int*   idxs   = (int*)(ws + IDX_OFF);
    float* z2     = (float*)(ws + Z2_OFF);

    float* out_zq   = (float*)d_out;
    float* out_idx  = out_zq + (size_t)NROWS * CDIM;
    float* out_loss = out_idx + NROWS;

    hipMemsetAsync(loss, 0, sizeof(float), stream);

    vq_bias<<<KCODES / 256, 256, 0, stream>>>(table, bias);

    dim3 grid(NROWS / ROWS_PER_BLOCK, KP);
    vq_main<<<grid, TPB, 0, stream>>>(z, table, bias, scores, idxs, z2);

    vq_combine<<<NROWS / 256, 256, 0, stream>>>(scores, idxs, z2, table,
                                                out_zq, out_idx, loss);

    vq_finalize<<<1, 1, 0, stream>>>(loss, out_loss);
}